// Round 7
// baseline (3651.624 us; speedup 1.0000x reference)
//
#include <hip/hip_runtime.h>

#define IN_DIM 8
#define HID 32
#define OUT_DIM 32

// ws layout (4-byte units):
//  [0..7] ch sum  [8..15] ch sumsq  [16..23] mean  [24..31] rstd  [32] int64-mode
//  [64 ..)            int hist[N]
//  [64+N ..)          int row_start[N]
//  [64+2N ..)         int cursor[N]
//  [64+3N ..)         int bsums[1024]
//  [64+3N+1024 ..)    int eid[E]
//  then               float msg[E*32]
// Fallback (small ws): only [0..32] used; agg lives in d_out.

__global__ void init_kernel(float* ws, const int* __restrict__ ei_raw, int two_e) {
  __shared__ int s_nonzero;
  if (threadIdx.x == 0) s_nonzero = 0;
  __syncthreads();
  // int64 storage => all hi (odd) 32-bit words are 0 (indices < 2^31)
  int nz = 0;
  for (int i = threadIdx.x; i < 2048 && (2 * i + 1) < 2 * two_e; i += blockDim.x) {
    if (ei_raw[2 * i + 1] != 0) nz = 1;
  }
  if (nz) atomicOr(&s_nonzero, 1);
  __syncthreads();
  if (threadIdx.x == 0) ((int*)ws)[32] = (s_nonzero == 0) ? 1 : 0;
}

__global__ void stats_kernel(const float* __restrict__ x, int n, float* ws) {
  __shared__ float ssum[8], ssq[8];
  if (threadIdx.x < 8) { ssum[threadIdx.x] = 0.f; ssq[threadIdx.x] = 0.f; }
  __syncthreads();
  int total = n * IN_DIM;
  int c = threadIdx.x & 7;  // grid*block divisible by 8 -> channel fixed
  float s = 0.f, s2 = 0.f;
  for (int i = blockIdx.x * blockDim.x + threadIdx.x; i < total;
       i += gridDim.x * blockDim.x) {
    float v = x[i];
    s += v; s2 += v * v;
  }
  atomicAdd(&ssum[c], s);
  atomicAdd(&ssq[c], s2);
  __syncthreads();
  if (threadIdx.x < 8) {
    atomicAdd(&ws[threadIdx.x], ssum[threadIdx.x]);
    atomicAdd(&ws[8 + threadIdx.x], ssq[threadIdx.x]);
  }
}

__global__ void finalize_stats(float* ws, float inv_n) {
  int t = threadIdx.x;
  if (t < 8) {
    float mean = ws[t] * inv_n;
    float var = ws[8 + t] * inv_n - mean * mean;
    ws[16 + t] = mean;
    ws[24 + t] = rsqrtf(var + 1e-5f);
  }
}

// ---------- sort-by-dst machinery (gather path) ----------

__global__ void hist_kernel(const int* __restrict__ ei_raw, const float* __restrict__ ws,
                            int* __restrict__ hist, int nE) {
  int mode64 = ((const int*)ws)[32];
  for (int e = blockIdx.x * blockDim.x + threadIdx.x; e < nE;
       e += gridDim.x * blockDim.x) {
    int dst = mode64 ? ei_raw[2 * (nE + e)] : ei_raw[nE + e];
    atomicAdd(&hist[dst], 1);
  }
}

__global__ void scan1_kernel(const int* __restrict__ hist, int* __restrict__ row_start,
                             int* __restrict__ bsums, int n) {
  __shared__ int s[1024];
  int i = blockIdx.x * 1024 + threadIdx.x;
  int v = (i < n) ? hist[i] : 0;
  s[threadIdx.x] = v;
  __syncthreads();
  for (int off = 1; off < 1024; off <<= 1) {
    int t = (threadIdx.x >= off) ? s[threadIdx.x - off] : 0;
    __syncthreads();
    s[threadIdx.x] += t;
    __syncthreads();
  }
  if (i < n) row_start[i] = s[threadIdx.x] - v;  // exclusive within block
  if (threadIdx.x == 1023) bsums[blockIdx.x] = s[1023];
}

__global__ void scan2_kernel(int* __restrict__ bsums, int nb) {
  __shared__ int s[1024];
  int v = (threadIdx.x < nb) ? bsums[threadIdx.x] : 0;
  s[threadIdx.x] = v;
  __syncthreads();
  for (int off = 1; off < 1024; off <<= 1) {
    int t = (threadIdx.x >= off) ? s[threadIdx.x - off] : 0;
    __syncthreads();
    s[threadIdx.x] += t;
    __syncthreads();
  }
  if (threadIdx.x < nb) bsums[threadIdx.x] = s[threadIdx.x] - v;  // exclusive
}

__global__ void scan3_kernel(int* __restrict__ row_start, int* __restrict__ cursor,
                             const int* __restrict__ bsums, int n) {
  int i = blockIdx.x * blockDim.x + threadIdx.x;
  if (i < n) {
    int r = row_start[i] + bsums[i >> 10];
    row_start[i] = r;
    cursor[i] = r;
  }
}

__global__ void scatter_kernel(const int* __restrict__ ei_raw, const float* __restrict__ ws,
                               int* __restrict__ cursor, int* __restrict__ eid, int nE) {
  int mode64 = ((const int*)ws)[32];
  for (int e = blockIdx.x * blockDim.x + threadIdx.x; e < nE;
       e += gridDim.x * blockDim.x) {
    int dst = mode64 ? ei_raw[2 * (nE + e)] : ei_raw[nE + e];
    int pos = atomicAdd(&cursor[dst], 1);
    eid[pos] = e;
  }
}

// ---------- edge MLP -> msg (no atomics; 2 edges/thread share weight broadcasts) ----------
__global__ __launch_bounds__(256, 4) void edge_msg_kernel(
    const float* __restrict__ ea, const float* __restrict__ x,
    const float* __restrict__ W1, const float* __restrict__ b1,
    const float* __restrict__ W2, const float* __restrict__ b2,
    const float* __restrict__ W3, const float* __restrict__ b3,
    const float* __restrict__ ws, const int* __restrict__ ei_raw,
    float* __restrict__ msg, int nE, int T) {
  __shared__ float sW1[256];
  __shared__ float sW2[1024];
  __shared__ float sW3T[8192];  // sW3T[(i*32+o)*32 + k] = W3[k*256 + i*32 + o]
  __shared__ float sB1[32], sB2[32], sB3[256];

  for (int i = threadIdx.x; i < 256; i += 256) sW1[i] = W1[i];
  for (int i = threadIdx.x; i < 1024; i += 256) sW2[i] = W2[i];
  for (int i = threadIdx.x; i < 8192; i += 256) {
    int k = i >> 8, j = i & 255;
    sW3T[j * 32 + k] = W3[i];
  }
  if (threadIdx.x < 32) { sB1[threadIdx.x] = b1[threadIdx.x]; sB2[threadIdx.x] = b2[threadIdx.x]; }
  for (int i = threadIdx.x; i < 256; i += 256) sB3[i] = b3[i];
  __syncthreads();

  int mode64 = ((const int*)ws)[32];
  int t = blockIdx.x * blockDim.x + threadIdx.x;
  if (t >= T) return;
  int e0 = t, e1 = t + T;           // both coalesced across lanes
  bool has1 = (e1 < nE);

  int src0 = mode64 ? ei_raw[2 * e0] : ei_raw[e0];
  int src1 = has1 ? (mode64 ? ei_raw[2 * e1] : ei_raw[e1]) : 0;

  float xsa[8], xsb[8];
#pragma unroll
  for (int i = 0; i < 8; ++i) {
    float m = ws[16 + i], r = ws[24 + i];
    xsa[i] = (x[(size_t)src0 * 8 + i] - m) * r;
    xsb[i] = has1 ? (x[(size_t)src1 * 8 + i] - m) * r : 0.f;
  }

  float h2a[32];
  {
    float a[8];
#pragma unroll
    for (int i = 0; i < 8; ++i) a[i] = ea[(size_t)e0 * 8 + i];
    float h1[32];
#pragma unroll
    for (int o = 0; o < 32; ++o) h1[o] = sB1[o];
#pragma unroll
    for (int i = 0; i < 8; ++i)
#pragma unroll
      for (int o = 0; o < 32; ++o) h1[o] += a[i] * sW1[i * 32 + o];
#pragma unroll
    for (int o = 0; o < 32; ++o) h1[o] = fmaxf(h1[o], 0.f);
#pragma unroll
    for (int o = 0; o < 32; ++o) h2a[o] = sB2[o];
#pragma unroll
    for (int k = 0; k < 32; ++k)
#pragma unroll
      for (int o = 0; o < 32; ++o) h2a[o] += h1[k] * sW2[k * 32 + o];
#pragma unroll
    for (int o = 0; o < 32; ++o) h2a[o] = fmaxf(h2a[o], 0.f);
  }
  float h2b[32];
  {
    float a[8];
#pragma unroll
    for (int i = 0; i < 8; ++i) a[i] = has1 ? ea[(size_t)e1 * 8 + i] : 0.f;
    float h1[32];
#pragma unroll
    for (int o = 0; o < 32; ++o) h1[o] = sB1[o];
#pragma unroll
    for (int i = 0; i < 8; ++i)
#pragma unroll
      for (int o = 0; o < 32; ++o) h1[o] += a[i] * sW1[i * 32 + o];
#pragma unroll
    for (int o = 0; o < 32; ++o) h1[o] = fmaxf(h1[o], 0.f);
#pragma unroll
    for (int o = 0; o < 32; ++o) h2b[o] = sB2[o];
#pragma unroll
    for (int k = 0; k < 32; ++k)
#pragma unroll
      for (int o = 0; o < 32; ++o) h2b[o] += h1[k] * sW2[k * 32 + o];
#pragma unroll
    for (int o = 0; o < 32; ++o) h2b[o] = fmaxf(h2b[o], 0.f);
  }

  float* m0p = msg + (size_t)e0 * 32;
  float* m1p = msg + (size_t)e1 * 32;
  for (int o = 0; o < 32; ++o) {  // runtime loop; reg arrays statically indexed
    float m0 = 0.f, m1 = 0.f;
#pragma unroll
    for (int i = 0; i < 8; ++i) {
      const float* wr = &sW3T[(i * 32 + o) * 32];
      float b = sB3[i * 32 + o];
      float acc0 = b, acc1 = b;
#pragma unroll
      for (int k = 0; k < 32; ++k) {
        float wv = wr[k];  // wave-uniform broadcast shared by both edges
        acc0 += h2a[k] * wv;
        acc1 += h2b[k] * wv;
      }
      m0 += xsa[i] * fmaxf(acc0, 0.f);
      m1 += xsb[i] * fmaxf(acc1, 0.f);
    }
    m0p[o] = m0;
    if (has1) m1p[o] = m1;
  }
}

// agg[n][o] = ncb[o] + sum_i xn[i]*Wroot[i][o] + sum_{incoming e} msg[e][o]
__global__ __launch_bounds__(256) void gather_kernel(
    const float* __restrict__ x, const float* __restrict__ Wroot,
    const float* __restrict__ ncb, const float* __restrict__ ws,
    const int* __restrict__ hist, const int* __restrict__ row_start,
    const int* __restrict__ eid, const float* __restrict__ msg,
    float* __restrict__ agg, int n) {
  __shared__ float sWr[256];
  __shared__ float sNcb[32];
  sWr[threadIdx.x] = Wroot[threadIdx.x];
  if (threadIdx.x < 32) sNcb[threadIdx.x] = ncb[threadIdx.x];
  __syncthreads();
  int gid = blockIdx.x * 256 + threadIdx.x;
  int node = gid >> 5, o = gid & 31;
  if (node >= n) return;
  float acc = sNcb[o];
#pragma unroll
  for (int i = 0; i < 8; ++i) {
    float xs = (x[(size_t)node * 8 + i] - ws[16 + i]) * ws[24 + i];
    acc += xs * sWr[i * 32 + o];
  }
  int start = row_start[node];
  int deg = hist[node];
  for (int p = 0; p < deg; ++p) {
    int e = eid[start + p];               // broadcast within 32-lane group
    acc += msg[(size_t)e * 32 + o];       // coalesced 128B per edge
  }
  agg[(size_t)node * 32 + o] = acc;
}

// ---------- fallback (atomic) path ----------
__global__ __launch_bounds__(256) void prep_kernel(
    const float* __restrict__ x, const float* __restrict__ Wroot,
    const float* __restrict__ ncb, const float* __restrict__ ws,
    float* __restrict__ agg, int n) {
  int gid = blockIdx.x * blockDim.x + threadIdx.x;
  int node = gid >> 5, o = gid & 31;
  if (node >= n) return;
  float acc = ncb[o];
#pragma unroll
  for (int i = 0; i < 8; ++i) {
    float xs = (x[(size_t)node * 8 + i] - ws[16 + i]) * ws[24 + i];
    acc += xs * Wroot[i * 32 + o];
  }
  agg[(size_t)node * 32 + o] = acc;
}

__global__ __launch_bounds__(256, 4) void edge_atomic_kernel(
    const float* __restrict__ ea, const float* __restrict__ x,
    const float* __restrict__ W1, const float* __restrict__ b1,
    const float* __restrict__ W2, const float* __restrict__ b2,
    const float* __restrict__ W3, const float* __restrict__ b3,
    const float* __restrict__ ws, const int* __restrict__ ei_raw,
    float* __restrict__ agg, int nE) {
  __shared__ float sW1[256];
  __shared__ float sW2[1024];
  __shared__ float sW3T[8192];
  __shared__ float sB1[32], sB2[32], sB3[256];
  for (int i = threadIdx.x; i < 256; i += 256) sW1[i] = W1[i];
  for (int i = threadIdx.x; i < 1024; i += 256) sW2[i] = W2[i];
  for (int i = threadIdx.x; i < 8192; i += 256) {
    int k = i >> 8, j = i & 255;
    sW3T[j * 32 + k] = W3[i];
  }
  if (threadIdx.x < 32) { sB1[threadIdx.x] = b1[threadIdx.x]; sB2[threadIdx.x] = b2[threadIdx.x]; }
  for (int i = threadIdx.x; i < 256; i += 256) sB3[i] = b3[i];
  __syncthreads();

  int mode64 = ((const int*)ws)[32];
  int e = blockIdx.x * blockDim.x + threadIdx.x;
  if (e >= nE) return;
  int src = mode64 ? ei_raw[2 * e] : ei_raw[e];
  int dst = mode64 ? ei_raw[2 * (nE + e)] : ei_raw[nE + e];

  float xs[8];
#pragma unroll
  for (int i = 0; i < 8; ++i)
    xs[i] = (x[(size_t)src * 8 + i] - ws[16 + i]) * ws[24 + i];
  float a[8];
#pragma unroll
  for (int i = 0; i < 8; ++i) a[i] = ea[(size_t)e * 8 + i];
  float h1[32];
#pragma unroll
  for (int o = 0; o < 32; ++o) h1[o] = sB1[o];
#pragma unroll
  for (int i = 0; i < 8; ++i)
#pragma unroll
    for (int o = 0; o < 32; ++o) h1[o] += a[i] * sW1[i * 32 + o];
#pragma unroll
  for (int o = 0; o < 32; ++o) h1[o] = fmaxf(h1[o], 0.f);
  float h2[32];
#pragma unroll
  for (int o = 0; o < 32; ++o) h2[o] = sB2[o];
#pragma unroll
  for (int k = 0; k < 32; ++k)
#pragma unroll
    for (int o = 0; o < 32; ++o) h2[o] += h1[k] * sW2[k * 32 + o];
#pragma unroll
  for (int o = 0; o < 32; ++o) h2[o] = fmaxf(h2[o], 0.f);

  float* aggd = agg + (size_t)dst * 32;
  for (int o = 0; o < 32; ++o) {
    float m = 0.f;
#pragma unroll
    for (int i = 0; i < 8; ++i) {
      const float* wr = &sW3T[(i * 32 + o) * 32];
      float acc = sB3[i * 32 + o];
#pragma unroll
      for (int k = 0; k < 32; ++k) acc += h2[k] * wr[k];
      m += xs[i] * fmaxf(acc, 0.f);
    }
    atomicAdd(&aggd[o], m);
  }
}

// out = relu(agg) -> relu(@Wl1+b) -> relu(@Wl2+b) -> @Wl3+b  (in-place on d_out)
__global__ __launch_bounds__(256) void mlp_kernel(
    const float* __restrict__ Wl1, const float* __restrict__ bl1,
    const float* __restrict__ Wl2, const float* __restrict__ bl2,
    const float* __restrict__ Wl3, const float* __restrict__ bl3,
    float* __restrict__ outp, int n) {
  __shared__ float sW[3][1024];
  __shared__ float sB[3][32];
  __shared__ float hbuf[256];
  for (int i = threadIdx.x; i < 1024; i += 256) {
    sW[0][i] = Wl1[i]; sW[1][i] = Wl2[i]; sW[2][i] = Wl3[i];
  }
  if (threadIdx.x < 32) {
    sB[0][threadIdx.x] = bl1[threadIdx.x];
    sB[1][threadIdx.x] = bl2[threadIdx.x];
    sB[2][threadIdx.x] = bl3[threadIdx.x];
  }
  __syncthreads();
  int gid = blockIdx.x * blockDim.x + threadIdx.x;
  int node = gid >> 5, o = gid & 31;
  bool active = node < n;
  float v = 0.f;
  if (active) v = fmaxf(outp[(size_t)node * 32 + o], 0.f);
  int base = threadIdx.x & ~31;
#pragma unroll
  for (int L = 0; L < 3; ++L) {
    __syncthreads();
    hbuf[threadIdx.x] = v;
    __syncthreads();
    float acc = sB[L][o];
#pragma unroll
    for (int k = 0; k < 32; ++k) acc += hbuf[base + k] * sW[L][k * 32 + o];
    v = (L < 2) ? fmaxf(acc, 0.f) : acc;
  }
  if (active) outp[(size_t)node * 32 + o] = v;
}

extern "C" void kernel_launch(void* const* d_in, const int* in_sizes, int n_in,
                              void* d_out, int out_size, void* d_ws, size_t ws_size,
                              hipStream_t stream) {
  const float* x  = (const float*)d_in[0];
  const int*   ei = (const int*)d_in[1];
  const float* ea = (const float*)d_in[2];
  const float* W1 = (const float*)d_in[3];  const float* b1  = (const float*)d_in[4];
  const float* W2 = (const float*)d_in[5];  const float* b2  = (const float*)d_in[6];
  const float* W3 = (const float*)d_in[7];  const float* b3  = (const float*)d_in[8];
  const float* Wroot = (const float*)d_in[9]; const float* ncb = (const float*)d_in[10];
  const float* Wl1 = (const float*)d_in[11]; const float* bl1 = (const float*)d_in[12];
  const float* Wl2 = (const float*)d_in[13]; const float* bl2 = (const float*)d_in[14];
  const float* Wl3 = (const float*)d_in[15]; const float* bl3 = (const float*)d_in[16];

  int n = in_sizes[0] / IN_DIM;
  int two_e = in_sizes[1];
  int nE = two_e / 2;
  int nb = (n + 1023) / 1024;

  float* ws = (float*)d_ws;
  float* outp = (float*)d_out;

  size_t ints_needed = 64 + 3 * (size_t)n + 1024 + (size_t)nE;
  size_t need = ints_needed * 4 + (size_t)nE * 32 * 4;
  bool gather_path = (ws_size >= need) && (nb <= 1024);

  int node_blocks = (n * 32 + 255) / 256;

  if (gather_path) {
    int* hist      = ((int*)d_ws) + 64;
    int* row_start = hist + n;
    int* cursor    = row_start + n;
    int* bsums     = cursor + n;
    int* eid       = bsums + 1024;
    float* msg     = (float*)(eid + nE);

    // zero stats + hist in one contiguous memset
    hipMemsetAsync(d_ws, 0, (64 + (size_t)n) * 4, stream);
    hipLaunchKernelGGL(init_kernel, dim3(1), dim3(256), 0, stream, ws, ei, two_e);
    hipLaunchKernelGGL(stats_kernel, dim3(256), dim3(256), 0, stream, x, n, ws);
    hipLaunchKernelGGL(finalize_stats, dim3(1), dim3(64), 0, stream, ws, 1.0f / (float)n);
    hipLaunchKernelGGL(hist_kernel, dim3(512), dim3(256), 0, stream, ei, ws, hist, nE);
    hipLaunchKernelGGL(scan1_kernel, dim3(nb), dim3(1024), 0, stream, hist, row_start, bsums, n);
    hipLaunchKernelGGL(scan2_kernel, dim3(1), dim3(1024), 0, stream, bsums, nb);
    hipLaunchKernelGGL(scan3_kernel, dim3((n + 255) / 256), dim3(256), 0, stream,
                       row_start, cursor, bsums, n);
    hipLaunchKernelGGL(scatter_kernel, dim3(512), dim3(256), 0, stream, ei, ws, cursor, eid, nE);

    int T = (nE + 1) / 2;
    int edge_blocks = (T + 255) / 256;
    hipLaunchKernelGGL(edge_msg_kernel, dim3(edge_blocks), dim3(256), 0, stream,
                       ea, x, W1, b1, W2, b2, W3, b3, ws, ei, msg, nE, T);
    hipLaunchKernelGGL(gather_kernel, dim3(node_blocks), dim3(256), 0, stream,
                       x, Wroot, ncb, ws, hist, row_start, eid, msg, outp, n);
    hipLaunchKernelGGL(mlp_kernel, dim3(node_blocks), dim3(256), 0, stream,
                       Wl1, bl1, Wl2, bl2, Wl3, bl3, outp, n);
  } else {
    hipMemsetAsync(d_ws, 0, 64 * 4, stream);
    hipLaunchKernelGGL(init_kernel, dim3(1), dim3(256), 0, stream, ws, ei, two_e);
    hipLaunchKernelGGL(stats_kernel, dim3(256), dim3(256), 0, stream, x, n, ws);
    hipLaunchKernelGGL(finalize_stats, dim3(1), dim3(64), 0, stream, ws, 1.0f / (float)n);
    hipLaunchKernelGGL(prep_kernel, dim3(node_blocks), dim3(256), 0, stream,
                       x, Wroot, ncb, ws, outp, n);
    int edge_blocks = (nE + 255) / 256;
    hipLaunchKernelGGL(edge_atomic_kernel, dim3(edge_blocks), dim3(256), 0, stream,
                       ea, x, W1, b1, W2, b2, W3, b3, ws, ei, outp, nE);
    hipLaunchKernelGGL(mlp_kernel, dim3(node_blocks), dim3(256), 0, stream,
                       Wl1, bl1, Wl2, bl2, Wl3, bl3, outp, n);
  }
}

// Round 9
// 3576.431 us; speedup vs baseline: 1.0210x; 1.0210x over previous
//
#include <hip/hip_runtime.h>

#define IN_DIM 8
#define HID 32
#define OUT_DIM 32

// ws layout (4-byte units):
//  [0..7] ch sum  [8..15] ch sumsq  [16..23] mean  [24..31] rstd  [32] int64-mode
//  [64 ..)            int hist[N]
//  [64+N ..)          int row_start[N]
//  [64+2N ..)         int cursor[N]
//  [64+3N ..)         int bsums[1024]
//  [64+3N+1024 ..)    int eid[E]
//  then               float msg[E*32]
// Fallback (small ws): only [0..32] used; agg lives in d_out.

__global__ void init_kernel(float* ws, const int* __restrict__ ei_raw, int two_e) {
  __shared__ int s_nonzero;
  if (threadIdx.x == 0) s_nonzero = 0;
  __syncthreads();
  // int64 storage => all hi (odd) 32-bit words are 0 (indices < 2^31)
  int nz = 0;
  for (int i = threadIdx.x; i < 2048 && (2 * i + 1) < 2 * two_e; i += blockDim.x) {
    if (ei_raw[2 * i + 1] != 0) nz = 1;
  }
  if (nz) atomicOr(&s_nonzero, 1);
  __syncthreads();
  if (threadIdx.x == 0) ((int*)ws)[32] = (s_nonzero == 0) ? 1 : 0;
}

__global__ void stats_kernel(const float* __restrict__ x, int n, float* ws) {
  __shared__ float ssum[8], ssq[8];
  if (threadIdx.x < 8) { ssum[threadIdx.x] = 0.f; ssq[threadIdx.x] = 0.f; }
  __syncthreads();
  int total = n * IN_DIM;
  int c = threadIdx.x & 7;  // grid*block divisible by 8 -> channel fixed
  float s = 0.f, s2 = 0.f;
  for (int i = blockIdx.x * blockDim.x + threadIdx.x; i < total;
       i += gridDim.x * blockDim.x) {
    float v = x[i];
    s += v; s2 += v * v;
  }
  atomicAdd(&ssum[c], s);
  atomicAdd(&ssq[c], s2);
  __syncthreads();
  if (threadIdx.x < 8) {
    atomicAdd(&ws[threadIdx.x], ssum[threadIdx.x]);
    atomicAdd(&ws[8 + threadIdx.x], ssq[threadIdx.x]);
  }
}

__global__ void finalize_stats(float* ws, float inv_n) {
  int t = threadIdx.x;
  if (t < 8) {
    float mean = ws[t] * inv_n;
    float var = ws[8 + t] * inv_n - mean * mean;
    ws[16 + t] = mean;
    ws[24 + t] = rsqrtf(var + 1e-5f);
  }
}

// ---------- sort-by-dst machinery (gather path) ----------

__global__ void hist_kernel(const int* __restrict__ ei_raw, const float* __restrict__ ws,
                            int* __restrict__ hist, int nE) {
  int mode64 = ((const int*)ws)[32];
  for (int e = blockIdx.x * blockDim.x + threadIdx.x; e < nE;
       e += gridDim.x * blockDim.x) {
    int dst = mode64 ? ei_raw[2 * (nE + e)] : ei_raw[nE + e];
    atomicAdd(&hist[dst], 1);
  }
}

__global__ void scan1_kernel(const int* __restrict__ hist, int* __restrict__ row_start,
                             int* __restrict__ bsums, int n) {
  __shared__ int s[1024];
  int i = blockIdx.x * 1024 + threadIdx.x;
  int v = (i < n) ? hist[i] : 0;
  s[threadIdx.x] = v;
  __syncthreads();
  for (int off = 1; off < 1024; off <<= 1) {
    int t = (threadIdx.x >= off) ? s[threadIdx.x - off] : 0;
    __syncthreads();
    s[threadIdx.x] += t;
    __syncthreads();
  }
  if (i < n) row_start[i] = s[threadIdx.x] - v;  // exclusive within block
  if (threadIdx.x == 1023) bsums[blockIdx.x] = s[1023];
}

__global__ void scan2_kernel(int* __restrict__ bsums, int nb) {
  __shared__ int s[1024];
  int v = (threadIdx.x < nb) ? bsums[threadIdx.x] : 0;
  s[threadIdx.x] = v;
  __syncthreads();
  for (int off = 1; off < 1024; off <<= 1) {
    int t = (threadIdx.x >= off) ? s[threadIdx.x - off] : 0;
    __syncthreads();
    s[threadIdx.x] += t;
    __syncthreads();
  }
  if (threadIdx.x < nb) bsums[threadIdx.x] = s[threadIdx.x] - v;  // exclusive
}

__global__ void scan3_kernel(int* __restrict__ row_start, int* __restrict__ cursor,
                             const int* __restrict__ bsums, int n) {
  int i = blockIdx.x * blockDim.x + threadIdx.x;
  if (i < n) {
    int r = row_start[i] + bsums[i >> 10];
    row_start[i] = r;
    cursor[i] = r;
  }
}

__global__ void scatter_kernel(const int* __restrict__ ei_raw, const float* __restrict__ ws,
                               int* __restrict__ cursor, int* __restrict__ eid, int nE) {
  int mode64 = ((const int*)ws)[32];
  for (int e = blockIdx.x * blockDim.x + threadIdx.x; e < nE;
       e += gridDim.x * blockDim.x) {
    int dst = mode64 ? ei_raw[2 * (nE + e)] : ei_raw[nE + e];
    int pos = atomicAdd(&cursor[dst], 1);
    eid[pos] = e;
  }
}

// ---------- edge MLP -> msg (no atomics; 2 edges/thread share weight broadcasts) ----
// NO min-waves hint: round-7 counters showed __launch_bounds__(256,4) forced the
// ~150-reg live set into scratch (VGPR=64, 11.7 GB HBM scratch traffic, VALUBusy 4%).
__global__ __launch_bounds__(256) void edge_msg_kernel(
    const float* __restrict__ ea, const float* __restrict__ x,
    const float* __restrict__ W1, const float* __restrict__ b1,
    const float* __restrict__ W2, const float* __restrict__ b2,
    const float* __restrict__ W3, const float* __restrict__ b3,
    const float* __restrict__ ws, const int* __restrict__ ei_raw,
    float* __restrict__ msg, int nE, int T) {
  __shared__ float sW1[256];
  __shared__ float sW2[1024];
  __shared__ float sW3T[8192];  // sW3T[(i*32+o)*32 + k] = W3[k*256 + i*32 + o]
  __shared__ float sB1[32], sB2[32], sB3[256];

  for (int i = threadIdx.x; i < 256; i += 256) sW1[i] = W1[i];
  for (int i = threadIdx.x; i < 1024; i += 256) sW2[i] = W2[i];
  for (int i = threadIdx.x; i < 8192; i += 256) {
    int k = i >> 8, j = i & 255;
    sW3T[j * 32 + k] = W3[i];
  }
  if (threadIdx.x < 32) { sB1[threadIdx.x] = b1[threadIdx.x]; sB2[threadIdx.x] = b2[threadIdx.x]; }
  for (int i = threadIdx.x; i < 256; i += 256) sB3[i] = b3[i];
  __syncthreads();

  int mode64 = ((const int*)ws)[32];
  int t = blockIdx.x * blockDim.x + threadIdx.x;
  if (t >= T) return;
  int e0 = t, e1 = t + T;           // both coalesced across lanes
  bool has1 = (e1 < nE);

  int src0 = mode64 ? ei_raw[2 * e0] : ei_raw[e0];
  int src1 = has1 ? (mode64 ? ei_raw[2 * e1] : ei_raw[e1]) : 0;

  float xsa[8], xsb[8];
#pragma unroll
  for (int i = 0; i < 8; ++i) {
    float m = ws[16 + i], r = ws[24 + i];
    xsa[i] = (x[(size_t)src0 * 8 + i] - m) * r;
    xsb[i] = has1 ? (x[(size_t)src1 * 8 + i] - m) * r : 0.f;
  }

  float h2a[32];
  {
    float a[8];
#pragma unroll
    for (int i = 0; i < 8; ++i) a[i] = ea[(size_t)e0 * 8 + i];
    float h1[32];
#pragma unroll
    for (int o = 0; o < 32; ++o) h1[o] = sB1[o];
#pragma unroll
    for (int i = 0; i < 8; ++i)
#pragma unroll
      for (int o = 0; o < 32; ++o) h1[o] += a[i] * sW1[i * 32 + o];
#pragma unroll
    for (int o = 0; o < 32; ++o) h1[o] = fmaxf(h1[o], 0.f);
#pragma unroll
    for (int o = 0; o < 32; ++o) h2a[o] = sB2[o];
#pragma unroll
    for (int k = 0; k < 32; ++k)
#pragma unroll
      for (int o = 0; o < 32; ++o) h2a[o] += h1[k] * sW2[k * 32 + o];
#pragma unroll
    for (int o = 0; o < 32; ++o) h2a[o] = fmaxf(h2a[o], 0.f);
  }
  float h2b[32];
  {
    float a[8];
#pragma unroll
    for (int i = 0; i < 8; ++i) a[i] = has1 ? ea[(size_t)e1 * 8 + i] : 0.f;
    float h1[32];
#pragma unroll
    for (int o = 0; o < 32; ++o) h1[o] = sB1[o];
#pragma unroll
    for (int i = 0; i < 8; ++i)
#pragma unroll
      for (int o = 0; o < 32; ++o) h1[o] += a[i] * sW1[i * 32 + o];
#pragma unroll
    for (int o = 0; o < 32; ++o) h1[o] = fmaxf(h1[o], 0.f);
#pragma unroll
    for (int o = 0; o < 32; ++o) h2b[o] = sB2[o];
#pragma unroll
    for (int k = 0; k < 32; ++k)
#pragma unroll
      for (int o = 0; o < 32; ++o) h2b[o] += h1[k] * sW2[k * 32 + o];
#pragma unroll
    for (int o = 0; o < 32; ++o) h2b[o] = fmaxf(h2b[o], 0.f);
  }

  // phase 3: 4 outputs per runtime iteration -> one float4 store each
  float4* m0p = (float4*)(msg + (size_t)e0 * 32);
  float4* m1p = (float4*)(msg + (size_t)e1 * 32);
  for (int o4 = 0; o4 < 8; ++o4) {  // runtime loop; reg arrays statically indexed
    float r0[4], r1[4];
#pragma unroll
    for (int oo = 0; oo < 4; ++oo) {
      int o = o4 * 4 + oo;
      float m0 = 0.f, m1 = 0.f;
#pragma unroll
      for (int i = 0; i < 8; ++i) {
        const float* wr = &sW3T[(i * 32 + o) * 32];
        float b = sB3[i * 32 + o];
        float acc0 = b, acc1 = b;
#pragma unroll
        for (int k = 0; k < 32; ++k) {
          float wv = wr[k];  // wave-uniform broadcast shared by both edges
          acc0 += h2a[k] * wv;
          acc1 += h2b[k] * wv;
        }
        m0 += xsa[i] * fmaxf(acc0, 0.f);
        m1 += xsb[i] * fmaxf(acc1, 0.f);
      }
      r0[oo] = m0; r1[oo] = m1;
    }
    m0p[o4] = make_float4(r0[0], r0[1], r0[2], r0[3]);
    if (has1) m1p[o4] = make_float4(r1[0], r1[1], r1[2], r1[3]);
  }
}

// agg[n][o] = ncb[o] + sum_i xn[i]*Wroot[i][o] + sum_{incoming e} msg[e][o]
__global__ __launch_bounds__(256) void gather_kernel(
    const float* __restrict__ x, const float* __restrict__ Wroot,
    const float* __restrict__ ncb, const float* __restrict__ ws,
    const int* __restrict__ hist, const int* __restrict__ row_start,
    const int* __restrict__ eid, const float* __restrict__ msg,
    float* __restrict__ agg, int n) {
  __shared__ float sWr[256];
  __shared__ float sNcb[32];
  sWr[threadIdx.x] = Wroot[threadIdx.x];
  if (threadIdx.x < 32) sNcb[threadIdx.x] = ncb[threadIdx.x];
  __syncthreads();
  int gid = blockIdx.x * 256 + threadIdx.x;
  int node = gid >> 5, o = gid & 31;
  if (node >= n) return;
  float acc = sNcb[o];
#pragma unroll
  for (int i = 0; i < 8; ++i) {
    float xs = (x[(size_t)node * 8 + i] - ws[16 + i]) * ws[24 + i];
    acc += xs * sWr[i * 32 + o];
  }
  int start = row_start[node];
  int deg = hist[node];
  for (int p = 0; p < deg; ++p) {
    int e = eid[start + p];               // broadcast within 32-lane group
    acc += msg[(size_t)e * 32 + o];       // coalesced 128B per edge
  }
  agg[(size_t)node * 32 + o] = acc;
}

// ---------- fallback (atomic) path ----------
__global__ __launch_bounds__(256) void prep_kernel(
    const float* __restrict__ x, const float* __restrict__ Wroot,
    const float* __restrict__ ncb, const float* __restrict__ ws,
    float* __restrict__ agg, int n) {
  int gid = blockIdx.x * blockDim.x + threadIdx.x;
  int node = gid >> 5, o = gid & 31;
  if (node >= n) return;
  float acc = ncb[o];
#pragma unroll
  for (int i = 0; i < 8; ++i) {
    float xs = (x[(size_t)node * 8 + i] - ws[16 + i]) * ws[24 + i];
    acc += xs * Wroot[i * 32 + o];
  }
  agg[(size_t)node * 32 + o] = acc;
}

__global__ __launch_bounds__(256) void edge_atomic_kernel(
    const float* __restrict__ ea, const float* __restrict__ x,
    const float* __restrict__ W1, const float* __restrict__ b1,
    const float* __restrict__ W2, const float* __restrict__ b2,
    const float* __restrict__ W3, const float* __restrict__ b3,
    const float* __restrict__ ws, const int* __restrict__ ei_raw,
    float* __restrict__ agg, int nE) {
  __shared__ float sW1[256];
  __shared__ float sW2[1024];
  __shared__ float sW3T[8192];
  __shared__ float sB1[32], sB2[32], sB3[256];
  for (int i = threadIdx.x; i < 256; i += 256) sW1[i] = W1[i];
  for (int i = threadIdx.x; i < 1024; i += 256) sW2[i] = W2[i];
  for (int i = threadIdx.x; i < 8192; i += 256) {
    int k = i >> 8, j = i & 255;
    sW3T[j * 32 + k] = W3[i];
  }
  if (threadIdx.x < 32) { sB1[threadIdx.x] = b1[threadIdx.x]; sB2[threadIdx.x] = b2[threadIdx.x]; }
  for (int i = threadIdx.x; i < 256; i += 256) sB3[i] = b3[i];
  __syncthreads();

  int mode64 = ((const int*)ws)[32];
  int e = blockIdx.x * blockDim.x + threadIdx.x;
  if (e >= nE) return;
  int src = mode64 ? ei_raw[2 * e] : ei_raw[e];
  int dst = mode64 ? ei_raw[2 * (nE + e)] : ei_raw[nE + e];

  float xs[8];
#pragma unroll
  for (int i = 0; i < 8; ++i)
    xs[i] = (x[(size_t)src * 8 + i] - ws[16 + i]) * ws[24 + i];
  float a[8];
#pragma unroll
  for (int i = 0; i < 8; ++i) a[i] = ea[(size_t)e * 8 + i];
  float h1[32];
#pragma unroll
  for (int o = 0; o < 32; ++o) h1[o] = sB1[o];
#pragma unroll
  for (int i = 0; i < 8; ++i)
#pragma unroll
    for (int o = 0; o < 32; ++o) h1[o] += a[i] * sW1[i * 32 + o];
#pragma unroll
  for (int o = 0; o < 32; ++o) h1[o] = fmaxf(h1[o], 0.f);
  float h2[32];
#pragma unroll
  for (int o = 0; o < 32; ++o) h2[o] = sB2[o];
#pragma unroll
  for (int k = 0; k < 32; ++k)
#pragma unroll
    for (int o = 0; o < 32; ++o) h2[o] += h1[k] * sW2[k * 32 + o];
#pragma unroll
  for (int o = 0; o < 32; ++o) h2[o] = fmaxf(h2[o], 0.f);

  float* aggd = agg + (size_t)dst * 32;
  for (int o = 0; o < 32; ++o) {
    float m = 0.f;
#pragma unroll
    for (int i = 0; i < 8; ++i) {
      const float* wr = &sW3T[(i * 32 + o) * 32];
      float acc = sB3[i * 32 + o];
#pragma unroll
      for (int k = 0; k < 32; ++k) acc += h2[k] * wr[k];
      m += xs[i] * fmaxf(acc, 0.f);
    }
    atomicAdd(&aggd[o], m);
  }
}

// out = relu(agg) -> relu(@Wl1+b) -> relu(@Wl2+b) -> @Wl3+b  (in-place on d_out)
__global__ __launch_bounds__(256) void mlp_kernel(
    const float* __restrict__ Wl1, const float* __restrict__ bl1,
    const float* __restrict__ Wl2, const float* __restrict__ bl2,
    const float* __restrict__ Wl3, const float* __restrict__ bl3,
    float* __restrict__ outp, int n) {
  __shared__ float sW[3][1024];
  __shared__ float sB[3][32];
  __shared__ float hbuf[256];
  for (int i = threadIdx.x; i < 1024; i += 256) {
    sW[0][i] = Wl1[i]; sW[1][i] = Wl2[i]; sW[2][i] = Wl3[i];
  }
  if (threadIdx.x < 32) {
    sB[0][threadIdx.x] = bl1[threadIdx.x];
    sB[1][threadIdx.x] = bl2[threadIdx.x];
    sB[2][threadIdx.x] = bl3[threadIdx.x];
  }
  __syncthreads();
  int gid = blockIdx.x * blockDim.x + threadIdx.x;
  int node = gid >> 5, o = gid & 31;
  bool active = node < n;
  float v = 0.f;
  if (active) v = fmaxf(outp[(size_t)node * 32 + o], 0.f);
  int base = threadIdx.x & ~31;
#pragma unroll
  for (int L = 0; L < 3; ++L) {
    __syncthreads();
    hbuf[threadIdx.x] = v;
    __syncthreads();
    float acc = sB[L][o];
#pragma unroll
    for (int k = 0; k < 32; ++k) acc += hbuf[base + k] * sW[L][k * 32 + o];
    v = (L < 2) ? fmaxf(acc, 0.f) : acc;
  }
  if (active) outp[(size_t)node * 32 + o] = v;
}

extern "C" void kernel_launch(void* const* d_in, const int* in_sizes, int n_in,
                              void* d_out, int out_size, void* d_ws, size_t ws_size,
                              hipStream_t stream) {
  const float* x  = (const float*)d_in[0];
  const int*   ei = (const int*)d_in[1];
  const float* ea = (const float*)d_in[2];
  const float* W1 = (const float*)d_in[3];  const float* b1  = (const float*)d_in[4];
  const float* W2 = (const float*)d_in[5];  const float* b2  = (const float*)d_in[6];
  const float* W3 = (const float*)d_in[7];  const float* b3  = (const float*)d_in[8];
  const float* Wroot = (const float*)d_in[9]; const float* ncb = (const float*)d_in[10];
  const float* Wl1 = (const float*)d_in[11]; const float* bl1 = (const float*)d_in[12];
  const float* Wl2 = (const float*)d_in[13]; const float* bl2 = (const float*)d_in[14];
  const float* Wl3 = (const float*)d_in[15]; const float* bl3 = (const float*)d_in[16];

  int n = in_sizes[0] / IN_DIM;
  int two_e = in_sizes[1];
  int nE = two_e / 2;
  int nb = (n + 1023) / 1024;

  float* ws = (float*)d_ws;
  float* outp = (float*)d_out;

  size_t ints_needed = 64 + 3 * (size_t)n + 1024 + (size_t)nE;
  size_t need = ints_needed * 4 + (size_t)nE * 32 * 4;
  bool gather_path = (ws_size >= need) && (nb <= 1024);

  int node_blocks = (n * 32 + 255) / 256;

  if (gather_path) {
    int* hist      = ((int*)d_ws) + 64;
    int* row_start = hist + n;
    int* cursor    = row_start + n;
    int* bsums     = cursor + n;
    int* eid       = bsums + 1024;
    float* msg     = (float*)(eid + nE);

    // zero stats + hist in one contiguous memset
    hipMemsetAsync(d_ws, 0, (64 + (size_t)n) * 4, stream);
    hipLaunchKernelGGL(init_kernel, dim3(1), dim3(256), 0, stream, ws, ei, two_e);
    hipLaunchKernelGGL(stats_kernel, dim3(256), dim3(256), 0, stream, x, n, ws);
    hipLaunchKernelGGL(finalize_stats, dim3(1), dim3(64), 0, stream, ws, 1.0f / (float)n);
    hipLaunchKernelGGL(hist_kernel, dim3(512), dim3(256), 0, stream, ei, ws, hist, nE);
    hipLaunchKernelGGL(scan1_kernel, dim3(nb), dim3(1024), 0, stream, hist, row_start, bsums, n);
    hipLaunchKernelGGL(scan2_kernel, dim3(1), dim3(1024), 0, stream, bsums, nb);
    hipLaunchKernelGGL(scan3_kernel, dim3((n + 255) / 256), dim3(256), 0, stream,
                       row_start, cursor, bsums, n);
    hipLaunchKernelGGL(scatter_kernel, dim3(512), dim3(256), 0, stream, ei, ws, cursor, eid, nE);

    int T = (nE + 1) / 2;
    int edge_blocks = (T + 255) / 256;
    hipLaunchKernelGGL(edge_msg_kernel, dim3(edge_blocks), dim3(256), 0, stream,
                       ea, x, W1, b1, W2, b2, W3, b3, ws, ei, msg, nE, T);
    hipLaunchKernelGGL(gather_kernel, dim3(node_blocks), dim3(256), 0, stream,
                       x, Wroot, ncb, ws, hist, row_start, eid, msg, outp, n);
    hipLaunchKernelGGL(mlp_kernel, dim3(node_blocks), dim3(256), 0, stream,
                       Wl1, bl1, Wl2, bl2, Wl3, bl3, outp, n);
  } else {
    hipMemsetAsync(d_ws, 0, 64 * 4, stream);
    hipLaunchKernelGGL(init_kernel, dim3(1), dim3(256), 0, stream, ws, ei, two_e);
    hipLaunchKernelGGL(stats_kernel, dim3(256), dim3(256), 0, stream, x, n, ws);
    hipLaunchKernelGGL(finalize_stats, dim3(1), dim3(64), 0, stream, ws, 1.0f / (float)n);
    hipLaunchKernelGGL(prep_kernel, dim3(node_blocks), dim3(256), 0, stream,
                       x, Wroot, ncb, ws, outp, n);
    int edge_blocks = (nE + 255) / 256;
    hipLaunchKernelGGL(edge_atomic_kernel, dim3(edge_blocks), dim3(256), 0, stream,
                       ea, x, W1, b1, W2, b2, W3, b3, ws, ei, outp, nE);
    hipLaunchKernelGGL(mlp_kernel, dim3(node_blocks), dim3(256), 0, stream,
                       Wl1, bl1, Wl2, bl2, Wl3, bl3, outp, n);
  }
}

// Round 13
// 576.816 us; speedup vs baseline: 6.3307x; 6.2003x over previous
//
#include <hip/hip_runtime.h>

#define IN_DIM 8
#define HID 32
#define OUT_DIM 32

// ws layout (4-byte units):
//  [0..7] ch sum  [8..15] ch sumsq  [16..23] mean  [24..31] rstd  [32] int64-mode
//  [64 ..)            int hist[N]
//  [64+N ..)          int row_start[N]
//  [64+2N ..)         int cursor[N]
//  [64+3N ..)         int bsums[1024]
//  [64+3N+1024 ..)    int eid[E]
//  then               float msg[E*32]
// Fallback (small ws): only [0..32] used; agg lives in d_out.

__global__ void init_kernel(float* ws, const int* __restrict__ ei_raw, int two_e) {
  __shared__ int s_nonzero;
  if (threadIdx.x == 0) s_nonzero = 0;
  __syncthreads();
  // int64 storage => all hi (odd) 32-bit words are 0 (indices < 2^31)
  int nz = 0;
  for (int i = threadIdx.x; i < 2048 && (2 * i + 1) < 2 * two_e; i += blockDim.x) {
    if (ei_raw[2 * i + 1] != 0) nz = 1;
  }
  if (nz) atomicOr(&s_nonzero, 1);
  __syncthreads();
  if (threadIdx.x == 0) ((int*)ws)[32] = (s_nonzero == 0) ? 1 : 0;
}

__global__ void stats_kernel(const float* __restrict__ x, int n, float* ws) {
  __shared__ float ssum[8], ssq[8];
  if (threadIdx.x < 8) { ssum[threadIdx.x] = 0.f; ssq[threadIdx.x] = 0.f; }
  __syncthreads();
  int total = n * IN_DIM;
  int c = threadIdx.x & 7;  // grid*block divisible by 8 -> channel fixed
  float s = 0.f, s2 = 0.f;
  for (int i = blockIdx.x * blockDim.x + threadIdx.x; i < total;
       i += gridDim.x * blockDim.x) {
    float v = x[i];
    s += v; s2 += v * v;
  }
  atomicAdd(&ssum[c], s);
  atomicAdd(&ssq[c], s2);
  __syncthreads();
  if (threadIdx.x < 8) {
    atomicAdd(&ws[threadIdx.x], ssum[threadIdx.x]);
    atomicAdd(&ws[8 + threadIdx.x], ssq[threadIdx.x]);
  }
}

__global__ void finalize_stats(float* ws, float inv_n) {
  int t = threadIdx.x;
  if (t < 8) {
    float mean = ws[t] * inv_n;
    float var = ws[8 + t] * inv_n - mean * mean;
    ws[16 + t] = mean;
    ws[24 + t] = rsqrtf(var + 1e-5f);
  }
}

// ---------- sort-by-dst machinery (gather path) ----------

__global__ void hist_kernel(const int* __restrict__ ei_raw, const float* __restrict__ ws,
                            int* __restrict__ hist, int nE) {
  int mode64 = ((const int*)ws)[32];
  for (int e = blockIdx.x * blockDim.x + threadIdx.x; e < nE;
       e += gridDim.x * blockDim.x) {
    int dst = mode64 ? ei_raw[2 * (nE + e)] : ei_raw[nE + e];
    atomicAdd(&hist[dst], 1);
  }
}

__global__ void scan1_kernel(const int* __restrict__ hist, int* __restrict__ row_start,
                             int* __restrict__ bsums, int n) {
  __shared__ int s[1024];
  int i = blockIdx.x * 1024 + threadIdx.x;
  int v = (i < n) ? hist[i] : 0;
  s[threadIdx.x] = v;
  __syncthreads();
  for (int off = 1; off < 1024; off <<= 1) {
    int t = (threadIdx.x >= off) ? s[threadIdx.x - off] : 0;
    __syncthreads();
    s[threadIdx.x] += t;
    __syncthreads();
  }
  if (i < n) row_start[i] = s[threadIdx.x] - v;  // exclusive within block
  if (threadIdx.x == 1023) bsums[blockIdx.x] = s[1023];
}

__global__ void scan2_kernel(int* __restrict__ bsums, int nb) {
  __shared__ int s[1024];
  int v = (threadIdx.x < nb) ? bsums[threadIdx.x] : 0;
  s[threadIdx.x] = v;
  __syncthreads();
  for (int off = 1; off < 1024; off <<= 1) {
    int t = (threadIdx.x >= off) ? s[threadIdx.x - off] : 0;
    __syncthreads();
    s[threadIdx.x] += t;
    __syncthreads();
  }
  if (threadIdx.x < nb) bsums[threadIdx.x] = s[threadIdx.x] - v;  // exclusive
}

__global__ void scan3_kernel(int* __restrict__ row_start, int* __restrict__ cursor,
                             const int* __restrict__ bsums, int n) {
  int i = blockIdx.x * blockDim.x + threadIdx.x;
  if (i < n) {
    int r = row_start[i] + bsums[i >> 10];
    row_start[i] = r;
    cursor[i] = r;
  }
}

__global__ void scatter_kernel(const int* __restrict__ ei_raw, const float* __restrict__ ws,
                               int* __restrict__ cursor, int* __restrict__ eid, int nE) {
  int mode64 = ((const int*)ws)[32];
  for (int e = blockIdx.x * blockDim.x + threadIdx.x; e < nE;
       e += gridDim.x * blockDim.x) {
    int dst = mode64 ? ei_raw[2 * (nE + e)] : ei_raw[nE + e];
    int pos = atomicAdd(&cursor[dst], 1);
    eid[pos] = e;
  }
}

// ---------- edge MLP -> msg (no atomics; 1 edge/thread, round-2 compute body) ----
// Round-9 lesson: the 2-edge body's 2048-stmt unroll silently failed -> reg arrays
// demoted to scratch (9.2 GB traffic, VALUBusy 5%). Revert to the 1-edge body.
// msg[e][32] stores are stride-128B per lane, so stage the block's tile in LDS
// (+1 pad, conflict-free) and flush coalesced.
__global__ __launch_bounds__(256) void edge_msg_kernel(
    const float* __restrict__ ea, const float* __restrict__ x,
    const float* __restrict__ W1, const float* __restrict__ b1,
    const float* __restrict__ W2, const float* __restrict__ b2,
    const float* __restrict__ W3, const float* __restrict__ b3,
    const float* __restrict__ ws, const int* __restrict__ ei_raw,
    float* __restrict__ msg, int nE) {
  __shared__ float sW1[256];
  __shared__ float sW2[1024];
  __shared__ float sW3T[8192];  // sW3T[(i*32+o)*32 + k] = W3[k*256 + i*32 + o]
  __shared__ float sB1[32], sB2[32], sB3[256];
  __shared__ float sMsg[256 * 33];  // +1 pad: bank (t+o)%32, conflict-free

  for (int i = threadIdx.x; i < 256; i += 256) sW1[i] = W1[i];
  for (int i = threadIdx.x; i < 1024; i += 256) sW2[i] = W2[i];
  for (int i = threadIdx.x; i < 8192; i += 256) {
    int k = i >> 8, j = i & 255;  // coalesced read of W3[k][j]
    sW3T[j * 32 + k] = W3[i];
  }
  if (threadIdx.x < 32) { sB1[threadIdx.x] = b1[threadIdx.x]; sB2[threadIdx.x] = b2[threadIdx.x]; }
  for (int i = threadIdx.x; i < 256; i += 256) sB3[i] = b3[i];
  __syncthreads();

  int mode64 = ((const int*)ws)[32];
  int e = blockIdx.x * 256 + threadIdx.x;
  bool active = (e < nE);
  int ec = active ? e : 0;  // clamp; inactive lanes compute garbage, never stored
  int src = mode64 ? ei_raw[2 * ec] : ei_raw[ec];

  float xs[8];
#pragma unroll
  for (int i = 0; i < 8; ++i)
    xs[i] = (x[(size_t)src * 8 + i] - ws[16 + i]) * ws[24 + i];
  float a[8];
#pragma unroll
  for (int i = 0; i < 8; ++i) a[i] = ea[(size_t)ec * 8 + i];

  float h1[32];
#pragma unroll
  for (int o = 0; o < 32; ++o) h1[o] = sB1[o];
#pragma unroll
  for (int i = 0; i < 8; ++i)
#pragma unroll
    for (int o = 0; o < 32; ++o) h1[o] += a[i] * sW1[i * 32 + o];
#pragma unroll
  for (int o = 0; o < 32; ++o) h1[o] = fmaxf(h1[o], 0.f);

  float h2[32];
#pragma unroll
  for (int o = 0; o < 32; ++o) h2[o] = sB2[o];
#pragma unroll
  for (int k = 0; k < 32; ++k)
#pragma unroll
    for (int o = 0; o < 32; ++o) h2[o] += h1[k] * sW2[k * 32 + o];
#pragma unroll
  for (int o = 0; o < 32; ++o) h2[o] = fmaxf(h2[o], 0.f);

  for (int o = 0; o < 32; ++o) {  // runtime loop; reg arrays statically indexed
    float m = 0.f;
#pragma unroll
    for (int i = 0; i < 8; ++i) {
      const float* wr = &sW3T[(i * 32 + o) * 32];
      float acc = sB3[i * 32 + o];
#pragma unroll
      for (int k = 0; k < 32; ++k) acc += h2[k] * wr[k];  // wave-uniform broadcast
      m += xs[i] * fmaxf(acc, 0.f);
    }
    sMsg[threadIdx.x * 33 + o] = m;
  }
  __syncthreads();

  // coalesced flush: consecutive threads -> consecutive global words
  size_t ebase = (size_t)blockIdx.x * 256;
  for (int f = threadIdx.x; f < 256 * 32; f += 256) {
    int el = f >> 5, o = f & 31;
    if (ebase + el < (size_t)nE) msg[ebase * 32 + f] = sMsg[el * 33 + o];
  }
}

// agg[n][o] = ncb[o] + sum_i xn[i]*Wroot[i][o] + sum_{incoming e} msg[e][o]
__global__ __launch_bounds__(256) void gather_kernel(
    const float* __restrict__ x, const float* __restrict__ Wroot,
    const float* __restrict__ ncb, const float* __restrict__ ws,
    const int* __restrict__ hist, const int* __restrict__ row_start,
    const int* __restrict__ eid, const float* __restrict__ msg,
    float* __restrict__ agg, int n) {
  __shared__ float sWr[256];
  __shared__ float sNcb[32];
  sWr[threadIdx.x] = Wroot[threadIdx.x];
  if (threadIdx.x < 32) sNcb[threadIdx.x] = ncb[threadIdx.x];
  __syncthreads();
  int gid = blockIdx.x * 256 + threadIdx.x;
  int node = gid >> 5, o = gid & 31;
  if (node >= n) return;
  float acc = sNcb[o];
#pragma unroll
  for (int i = 0; i < 8; ++i) {
    float xs = (x[(size_t)node * 8 + i] - ws[16 + i]) * ws[24 + i];
    acc += xs * sWr[i * 32 + o];
  }
  int start = row_start[node];
  int deg = hist[node];
  for (int p = 0; p < deg; ++p) {
    int e = eid[start + p];               // broadcast within 32-lane group
    acc += msg[(size_t)e * 32 + o];       // coalesced 128B per edge
  }
  agg[(size_t)node * 32 + o] = acc;
}

// ---------- fallback (atomic) path ----------
__global__ __launch_bounds__(256) void prep_kernel(
    const float* __restrict__ x, const float* __restrict__ Wroot,
    const float* __restrict__ ncb, const float* __restrict__ ws,
    float* __restrict__ agg, int n) {
  int gid = blockIdx.x * blockDim.x + threadIdx.x;
  int node = gid >> 5, o = gid & 31;
  if (node >= n) return;
  float acc = ncb[o];
#pragma unroll
  for (int i = 0; i < 8; ++i) {
    float xs = (x[(size_t)node * 8 + i] - ws[16 + i]) * ws[24 + i];
    acc += xs * Wroot[i * 32 + o];
  }
  agg[(size_t)node * 32 + o] = acc;
}

__global__ __launch_bounds__(256) void edge_atomic_kernel(
    const float* __restrict__ ea, const float* __restrict__ x,
    const float* __restrict__ W1, const float* __restrict__ b1,
    const float* __restrict__ W2, const float* __restrict__ b2,
    const float* __restrict__ W3, const float* __restrict__ b3,
    const float* __restrict__ ws, const int* __restrict__ ei_raw,
    float* __restrict__ agg, int nE) {
  __shared__ float sW1[256];
  __shared__ float sW2[1024];
  __shared__ float sW3T[8192];
  __shared__ float sB1[32], sB2[32], sB3[256];
  for (int i = threadIdx.x; i < 256; i += 256) sW1[i] = W1[i];
  for (int i = threadIdx.x; i < 1024; i += 256) sW2[i] = W2[i];
  for (int i = threadIdx.x; i < 8192; i += 256) {
    int k = i >> 8, j = i & 255;
    sW3T[j * 32 + k] = W3[i];
  }
  if (threadIdx.x < 32) { sB1[threadIdx.x] = b1[threadIdx.x]; sB2[threadIdx.x] = b2[threadIdx.x]; }
  for (int i = threadIdx.x; i < 256; i += 256) sB3[i] = b3[i];
  __syncthreads();

  int mode64 = ((const int*)ws)[32];
  int e = blockIdx.x * blockDim.x + threadIdx.x;
  if (e >= nE) return;
  int src = mode64 ? ei_raw[2 * e] : ei_raw[e];
  int dst = mode64 ? ei_raw[2 * (nE + e)] : ei_raw[nE + e];

  float xs[8];
#pragma unroll
  for (int i = 0; i < 8; ++i)
    xs[i] = (x[(size_t)src * 8 + i] - ws[16 + i]) * ws[24 + i];
  float a[8];
#pragma unroll
  for (int i = 0; i < 8; ++i) a[i] = ea[(size_t)e * 8 + i];
  float h1[32];
#pragma unroll
  for (int o = 0; o < 32; ++o) h1[o] = sB1[o];
#pragma unroll
  for (int i = 0; i < 8; ++i)
#pragma unroll
    for (int o = 0; o < 32; ++o) h1[o] += a[i] * sW1[i * 32 + o];
#pragma unroll
  for (int o = 0; o < 32; ++o) h1[o] = fmaxf(h1[o], 0.f);
  float h2[32];
#pragma unroll
  for (int o = 0; o < 32; ++o) h2[o] = sB2[o];
#pragma unroll
  for (int k = 0; k < 32; ++k)
#pragma unroll
    for (int o = 0; o < 32; ++o) h2[o] += h1[k] * sW2[k * 32 + o];
#pragma unroll
  for (int o = 0; o < 32; ++o) h2[o] = fmaxf(h2[o], 0.f);

  float* aggd = agg + (size_t)dst * 32;
  for (int o = 0; o < 32; ++o) {
    float m = 0.f;
#pragma unroll
    for (int i = 0; i < 8; ++i) {
      const float* wr = &sW3T[(i * 32 + o) * 32];
      float acc = sB3[i * 32 + o];
#pragma unroll
      for (int k = 0; k < 32; ++k) acc += h2[k] * wr[k];
      m += xs[i] * fmaxf(acc, 0.f);
    }
    atomicAdd(&aggd[o], m);
  }
}

// out = relu(agg) -> relu(@Wl1+b) -> relu(@Wl2+b) -> @Wl3+b  (in-place on d_out)
__global__ __launch_bounds__(256) void mlp_kernel(
    const float* __restrict__ Wl1, const float* __restrict__ bl1,
    const float* __restrict__ Wl2, const float* __restrict__ bl2,
    const float* __restrict__ Wl3, const float* __restrict__ bl3,
    float* __restrict__ outp, int n) {
  __shared__ float sW[3][1024];
  __shared__ float sB[3][32];
  __shared__ float hbuf[256];
  for (int i = threadIdx.x; i < 1024; i += 256) {
    sW[0][i] = Wl1[i]; sW[1][i] = Wl2[i]; sW[2][i] = Wl3[i];
  }
  if (threadIdx.x < 32) {
    sB[0][threadIdx.x] = bl1[threadIdx.x];
    sB[1][threadIdx.x] = bl2[threadIdx.x];
    sB[2][threadIdx.x] = bl3[threadIdx.x];
  }
  __syncthreads();
  int gid = blockIdx.x * blockDim.x + threadIdx.x;
  int node = gid >> 5, o = gid & 31;
  bool active = node < n;
  float v = 0.f;
  if (active) v = fmaxf(outp[(size_t)node * 32 + o], 0.f);
  int base = threadIdx.x & ~31;
#pragma unroll
  for (int L = 0; L < 3; ++L) {
    __syncthreads();
    hbuf[threadIdx.x] = v;
    __syncthreads();
    float acc = sB[L][o];
#pragma unroll
    for (int k = 0; k < 32; ++k) acc += hbuf[base + k] * sW[L][k * 32 + o];
    v = (L < 2) ? fmaxf(acc, 0.f) : acc;
  }
  if (active) outp[(size_t)node * 32 + o] = v;
}

extern "C" void kernel_launch(void* const* d_in, const int* in_sizes, int n_in,
                              void* d_out, int out_size, void* d_ws, size_t ws_size,
                              hipStream_t stream) {
  const float* x  = (const float*)d_in[0];
  const int*   ei = (const int*)d_in[1];
  const float* ea = (const float*)d_in[2];
  const float* W1 = (const float*)d_in[3];  const float* b1  = (const float*)d_in[4];
  const float* W2 = (const float*)d_in[5];  const float* b2  = (const float*)d_in[6];
  const float* W3 = (const float*)d_in[7];  const float* b3  = (const float*)d_in[8];
  const float* Wroot = (const float*)d_in[9]; const float* ncb = (const float*)d_in[10];
  const float* Wl1 = (const float*)d_in[11]; const float* bl1 = (const float*)d_in[12];
  const float* Wl2 = (const float*)d_in[13]; const float* bl2 = (const float*)d_in[14];
  const float* Wl3 = (const float*)d_in[15]; const float* bl3 = (const float*)d_in[16];

  int n = in_sizes[0] / IN_DIM;
  int two_e = in_sizes[1];
  int nE = two_e / 2;
  int nb = (n + 1023) / 1024;

  float* ws = (float*)d_ws;
  float* outp = (float*)d_out;

  size_t ints_needed = 64 + 3 * (size_t)n + 1024 + (size_t)nE;
  size_t need = ints_needed * 4 + (size_t)nE * 32 * 4;
  bool gather_path = (ws_size >= need) && (nb <= 1024);

  int node_blocks = (n * 32 + 255) / 256;

  if (gather_path) {
    int* hist      = ((int*)d_ws) + 64;
    int* row_start = hist + n;
    int* cursor    = row_start + n;
    int* bsums     = cursor + n;
    int* eid       = bsums + 1024;
    float* msg     = (float*)(eid + nE);

    // zero stats + hist in one contiguous memset
    hipMemsetAsync(d_ws, 0, (64 + (size_t)n) * 4, stream);
    hipLaunchKernelGGL(init_kernel, dim3(1), dim3(256), 0, stream, ws, ei, two_e);
    hipLaunchKernelGGL(stats_kernel, dim3(256), dim3(256), 0, stream, x, n, ws);
    hipLaunchKernelGGL(finalize_stats, dim3(1), dim3(64), 0, stream, ws, 1.0f / (float)n);
    hipLaunchKernelGGL(hist_kernel, dim3(512), dim3(256), 0, stream, ei, ws, hist, nE);
    hipLaunchKernelGGL(scan1_kernel, dim3(nb), dim3(1024), 0, stream, hist, row_start, bsums, n);
    hipLaunchKernelGGL(scan2_kernel, dim3(1), dim3(1024), 0, stream, bsums, nb);
    hipLaunchKernelGGL(scan3_kernel, dim3((n + 255) / 256), dim3(256), 0, stream,
                       row_start, cursor, bsums, n);
    hipLaunchKernelGGL(scatter_kernel, dim3(512), dim3(256), 0, stream, ei, ws, cursor, eid, nE);

    int edge_blocks = (nE + 255) / 256;
    hipLaunchKernelGGL(edge_msg_kernel, dim3(edge_blocks), dim3(256), 0, stream,
                       ea, x, W1, b1, W2, b2, W3, b3, ws, ei, msg, nE);
    hipLaunchKernelGGL(gather_kernel, dim3(node_blocks), dim3(256), 0, stream,
                       x, Wroot, ncb, ws, hist, row_start, eid, msg, outp, n);
    hipLaunchKernelGGL(mlp_kernel, dim3(node_blocks), dim3(256), 0, stream,
                       Wl1, bl1, Wl2, bl2, Wl3, bl3, outp, n);
  } else {
    hipMemsetAsync(d_ws, 0, 64 * 4, stream);
    hipLaunchKernelGGL(init_kernel, dim3(1), dim3(256), 0, stream, ws, ei, two_e);
    hipLaunchKernelGGL(stats_kernel, dim3(256), dim3(256), 0, stream, x, n, ws);
    hipLaunchKernelGGL(finalize_stats, dim3(1), dim3(64), 0, stream, ws, 1.0f / (float)n);
    hipLaunchKernelGGL(prep_kernel, dim3(node_blocks), dim3(256), 0, stream,
                       x, Wroot, ncb, ws, outp, n);
    int edge_blocks = (nE + 255) / 256;
    hipLaunchKernelGGL(edge_atomic_kernel, dim3(edge_blocks), dim3(256), 0, stream,
                       ea, x, W1, b1, W2, b2, W3, b3, ws, ei, outp, nE);
    hipLaunchKernelGGL(mlp_kernel, dim3(node_blocks), dim3(256), 0, stream,
                       Wl1, bl1, Wl2, bl2, Wl3, bl3, outp, n);
  }
}